// Round 3
// baseline (8345.573 us; speedup 1.0000x reference)
//
#include <hip/hip_runtime.h>

typedef unsigned short u16;
typedef __attribute__((ext_vector_type(8))) short short8;
typedef __attribute__((ext_vector_type(4))) float floatx4;

__device__ __forceinline__ u16 f2bf(float f) {
  union { float f; unsigned int u; } v; v.f = f;
  unsigned int r = v.u + 0x7FFFu + ((v.u >> 16) & 1u);
  return (u16)(r >> 16);
}
__device__ __forceinline__ float sigmoidf_(float x) {
  return 1.0f / (1.0f + __expf(-x));
}
__device__ __forceinline__ float tanhf_(float x) {
  float xx = fminf(fmaxf(x, -15.0f), 15.0f);
  float e = __expf(2.0f * xx);
  return (e - 1.0f) / (e + 1.0f);
}

// ---- batched tagged loads: issue WITHOUT wait (T14 issue-early pattern) ----
// All cross-WG traffic uses sc1 (MALL-coherent across all XCDs) — the exact
// load/store semantics hardware-validated in R1. Each u32 is {tag|bf16}:
// a stale read fails the tag check and retries (single-dword atomicity), so
// correctness is independent of WG->XCD placement (Guideline 16).
__device__ __forceinline__ void issue8_sc1(const unsigned int* p,
    uint4& r0, uint4& r1, uint4& r2, uint4& r3,
    uint4& r4, uint4& r5, uint4& r6, uint4& r7) {
  asm volatile(
      "global_load_dwordx4 %0, %8, off sc1\n\t"
      "global_load_dwordx4 %1, %8, off offset:16 sc1\n\t"
      "global_load_dwordx4 %2, %8, off offset:32 sc1\n\t"
      "global_load_dwordx4 %3, %8, off offset:48 sc1\n\t"
      "global_load_dwordx4 %4, %8, off offset:64 sc1\n\t"
      "global_load_dwordx4 %5, %8, off offset:80 sc1\n\t"
      "global_load_dwordx4 %6, %8, off offset:96 sc1\n\t"
      "global_load_dwordx4 %7, %8, off offset:112 sc1"
      : "=&v"(r0), "=&v"(r1), "=&v"(r2), "=&v"(r3),
        "=&v"(r4), "=&v"(r5), "=&v"(r6), "=&v"(r7)
      : "v"(p) : "memory");
}

// rule 18: sched_barrier(0) right after an inline-asm waitcnt, else hipcc may
// hoist register-only consumers above the wait.
#define WAITVM() do { asm volatile("s_waitcnt vmcnt(0)" ::: "memory"); \
                      __builtin_amdgcn_sched_barrier(0); } while (0)

__device__ __forceinline__ void st_dword_sc1(unsigned int* p, unsigned int v) {
  asm volatile("global_store_dword %0, %1, off sc1" :: "v"(p), "v"(v) : "memory");
}

__device__ __forceinline__ int tagok4(uint4 a, unsigned int tg) {
  return (a.x >> 16) == tg && (a.y >> 16) == tg && (a.z >> 16) == tg && (a.w >> 16) == tg;
}
__device__ __forceinline__ short8 pack8(uint4 a, uint4 b) {
  union { short8 v; unsigned int u[4]; } o;
  o.u[0] = (a.x & 0xFFFFu) | (a.y << 16);
  o.u[1] = (a.z & 0xFFFFu) | (a.w << 16);
  o.u[2] = (b.x & 0xFFFFu) | (b.y << 16);
  o.u[3] = (b.z & 0xFFFFu) | (b.w << 16);
  return o.v;
}

// LDS swizzles (kept from R1: bank conflicts 3.6e8 -> 8.4e6)
#define FW(kq, g) (((((kq) >> 2) << 1) ^ (g)) & 7)

// ---- fp32 -> bf16 bulk convert (x) ----
__global__ void convert_f32_bf16(const float* __restrict__ in, u16* __restrict__ out, int n8) {
  int idx = blockIdx.x * blockDim.x + threadIdx.x;
  if (idx >= n8) return;
  const float4* s = (const float4*)in + (size_t)idx * 2;
  float4 a = s[0], b = s[1];
  union { short8 v; u16 u[8]; } o;
  o.u[0] = f2bf(a.x); o.u[1] = f2bf(a.y); o.u[2] = f2bf(a.z); o.u[3] = f2bf(a.w);
  o.u[4] = f2bf(b.x); o.u[5] = f2bf(b.y); o.u[6] = f2bf(b.z); o.u[7] = f2bf(b.w);
  ((short8*)out)[idx] = o.v;
}

// ---- W [512][2048] fp32 -> Wt [2048][512] bf16 ----
__global__ void transpose_to_bf16(const float* __restrict__ W, u16* __restrict__ Wt) {
  __shared__ u16 tile[64][65];
  int kb = blockIdx.x * 64;
  int nb = blockIdx.y * 64;
  int tx = threadIdx.x & 63;
  int ty = threadIdx.x >> 6;
#pragma unroll
  for (int jj = 0; jj < 16; jj++) {
    int rr = ty + jj * 4;
    tile[tx][rr] = f2bf(W[(size_t)(kb + rr) * 2048 + nb + tx]);
  }
  __syncthreads();
#pragma unroll
  for (int jj = 0; jj < 16; jj++) {
    int rr = ty + jj * 4;
    Wt[(size_t)(nb + rr) * 512 + kb + tx] = tile[rr][tx];
  }
}

// ---- fused 2-layer persistent LSTM, tagged-word handoff ----
// 256 WGs (1/CU by 148KB LDS). Static roles from blockIdx (no XCC_ID, no
// atomics — liveness must not depend on placement): g8 = wg&7 selects the
// group (under round-robin dispatch each group shares an XCD — speed bonus
// only); layer = g8>>2, rb = g8&3, cg = wg>>3.
// Both layers have identical structure: input-phase MFMA + h-phase MFMA
// (layer0 computes x@Wx0 on the fly; no xz prepass).
__global__ __launch_bounds__(256) void lstm_fused(
    const u16* __restrict__ xbf,
    const u16* __restrict__ Wx0t, const u16* __restrict__ Wh0t,
    const u16* __restrict__ Wx1t, const u16* __restrict__ Wh1t,
    const float* __restrict__ b0, const float* __restrict__ b1,
    unsigned int* hb, unsigned int* y0u,
    float* __restrict__ out, float* __restrict__ hfin, float* __restrict__ cfin) {
  __shared__ short8 WA[16][4][64];    // 64KB: Wh slice
  __shared__ short8 WB[16][4][64];    // 64KB: Wx slice
  __shared__ short8 TILE[16][4][16];  // 16KB: input/h staging (swizzled)
  __shared__ float zbuf[16 * 68];     // 4.25KB

  int tid = threadIdx.x;
  int wg = blockIdx.x;
  int g8 = wg & 7;
  int layer = g8 >> 2;
  int rb = g8 & 3;
  int cg = wg >> 3;

  int lane = tid & 63, w = tid >> 6;
  int l15 = lane & 15, g = lane >> 4;
  int brow = rb * 16;
  int r = tid >> 4, j = tid & 15;     // elementwise/store mapping
  int mm = tid >> 4, kq = tid & 15;   // staging mapping
  int hcol = cg * 16 + j;

  // stage weights (plain cached loads; once)
  {
    int n = tid >> 2, q = tid & 3;
    int gate = n >> 4, nloc = n & 15;
    const u16* WhT = layer ? Wh1t : Wh0t;
    const u16* WxT = layer ? Wx1t : Wx0t;
    const short8* sh = (const short8*)(WhT + (size_t)(gate * 512 + cg * 16 + nloc) * 512) + q * 16;
    const short8* sx = (const short8*)(WxT + (size_t)(gate * 512 + cg * 16 + nloc) * 512) + q * 16;
#pragma unroll
    for (int i = 0; i < 16; i++)
      WA[q * 4 + (i >> 2)][i & 3][n ^ FW(q * 4 + (i >> 2), i & 3)] = sh[i];
#pragma unroll
    for (int i = 0; i < 16; i++)
      WB[q * 4 + (i >> 2)][i & 3][n ^ FW(q * 4 + (i >> 2), i & 3)] = sx[i];
  }

  const float* bias = layer ? b1 : b0;
  float br[4];
#pragma unroll
  for (int gate = 0; gate < 4; gate++) br[gate] = bias[gate * 512 + hcol];

  unsigned int* hbL = hb + (size_t)layer * 131072;  // [2][64][512] u32
  float* z = zbuf;
  float c = 0.0f;
  float* hfinL = hfin + layer * 32768;
  float* cfinL = cfin + layer * 32768;

  short8 xv0 = {}, xv1 = {}, xv2 = {}, xv3 = {};
  uint4 yr0 = {}, yr1 = {}, yr2 = {}, yr3 = {}, yr4 = {}, yr5 = {}, yr6 = {}, yr7 = {};
  uint4 hr0 = {}, hr1 = {}, hr2 = {}, hr3 = {}, hr4 = {}, hr5 = {}, hr6 = {}, hr7 = {};
  const unsigned int* yp_cur = nullptr;
  const unsigned int* hp_cur = nullptr;

  // prologue: issue input loads for t=0 (no h at t=0: h(-1)=0)
  if (layer == 0) {
    const short8* xsp = (const short8*)(xbf + (size_t)(brow + mm) * 1024 * 512) + kq * 4;
    xv0 = xsp[0]; xv1 = xsp[1]; xv2 = xsp[2]; xv3 = xsp[3];
  } else {
    yp_cur = y0u + (size_t)(brow + mm) * 1024 * 512 + kq * 32;
    issue8_sc1(yp_cur, yr0, yr1, yr2, yr3, yr4, yr5, yr6, yr7);
  }

  for (int t = 0; t < 1024; t++) {
    // ---- (A) input phase: complete/poll input, stage into TILE ----
    int ms = mm ^ (kq & 7);
    if (layer == 0) {
      TILE[kq][0][ms] = xv0; TILE[kq][1][ms] = xv1;
      TILE[kq][2][ms] = xv2; TILE[kq][3][ms] = xv3;
    } else {
      WAITVM();
      unsigned int tg = (unsigned int)(t + 1);  // y0(t) carries tag t+1
      while (1) {
        int ok = tagok4(yr0, tg) & tagok4(yr1, tg) & tagok4(yr2, tg) & tagok4(yr3, tg) &
                 tagok4(yr4, tg) & tagok4(yr5, tg) & tagok4(yr6, tg) & tagok4(yr7, tg);
        if (__all(ok)) break;
        issue8_sc1(yp_cur, yr0, yr1, yr2, yr3, yr4, yr5, yr6, yr7);
        WAITVM();
      }
      TILE[kq][0][ms] = pack8(yr0, yr1); TILE[kq][1][ms] = pack8(yr2, yr3);
      TILE[kq][2][ms] = pack8(yr4, yr5); TILE[kq][3][ms] = pack8(yr6, yr7);
    }
    __syncthreads();  // B1
    // ---- (B) input MFMA: acc = input @ Wx ----
    floatx4 a0 = (floatx4){0.f, 0.f, 0.f, 0.f};
    floatx4 a1 = (floatx4){0.f, 0.f, 0.f, 0.f};
#pragma unroll
    for (int kb = 0; kb < 16; kb += 2) {
      a0 = __builtin_amdgcn_mfma_f32_16x16x32_bf16(
          TILE[kb][g][l15 ^ (kb & 7)], WB[kb][g][(w * 16 + l15) ^ FW(kb, g)], a0, 0, 0, 0);
      a1 = __builtin_amdgcn_mfma_f32_16x16x32_bf16(
          TILE[kb + 1][g][l15 ^ ((kb + 1) & 7)], WB[kb + 1][g][(w * 16 + l15) ^ FW(kb + 1, g)],
          a1, 0, 0, 0);
    }
    __syncthreads();  // B2 (TILE free)
    // ---- (C)+(D) h phase (skipped at t=0: h(-1)=0) ----
    if (t > 0) {
      WAITVM();
      unsigned int tg = (unsigned int)t;  // h(t-1) carries tag t
      while (1) {
        int ok = tagok4(hr0, tg) & tagok4(hr1, tg) & tagok4(hr2, tg) & tagok4(hr3, tg) &
                 tagok4(hr4, tg) & tagok4(hr5, tg) & tagok4(hr6, tg) & tagok4(hr7, tg);
        if (__all(ok)) break;
        issue8_sc1(hp_cur, hr0, hr1, hr2, hr3, hr4, hr5, hr6, hr7);
        WAITVM();
      }
      TILE[kq][0][ms] = pack8(hr0, hr1); TILE[kq][1][ms] = pack8(hr2, hr3);
      TILE[kq][2][ms] = pack8(hr4, hr5); TILE[kq][3][ms] = pack8(hr6, hr7);
      __syncthreads();  // B3
#pragma unroll
      for (int kb = 0; kb < 16; kb += 2) {
        a0 = __builtin_amdgcn_mfma_f32_16x16x32_bf16(
            TILE[kb][g][l15 ^ (kb & 7)], WA[kb][g][(w * 16 + l15) ^ FW(kb, g)], a0, 0, 0, 0);
        a1 = __builtin_amdgcn_mfma_f32_16x16x32_bf16(
            TILE[kb + 1][g][l15 ^ ((kb + 1) & 7)], WA[kb + 1][g][(w * 16 + l15) ^ FW(kb + 1, g)],
            a1, 0, 0, 0);
      }
    }
    // ---- z to LDS ----
#pragma unroll
    for (int rr = 0; rr < 4; rr++) z[(g * 4 + rr) * 68 + w * 16 + l15] = a0[rr] + a1[rr];
    __syncthreads();  // B4
    // ---- (E) elementwise + tagged stores (fire-and-forget; tag+data one word) ----
    float zi = z[r * 68 + 0 + j] + br[0];
    float zf = z[r * 68 + 16 + j] + br[1];
    float zg = z[r * 68 + 32 + j] + br[2];
    float zo = z[r * 68 + 48 + j] + br[3];
    float ig = sigmoidf_(zi), fg = sigmoidf_(zf), og = sigmoidf_(zo);
    float gg = tanhf_(zg);
    c = fg * c + ig * gg;
    float hn = og * tanhf_(c);
    unsigned int word = ((unsigned int)(t + 1) << 16) | (unsigned int)f2bf(hn);
    st_dword_sc1(hbL + (size_t)((t + 1) & 1) * 32768 + (size_t)(brow + r) * 512 + hcol, word);
    if (layer == 0) {
      st_dword_sc1(y0u + ((size_t)(brow + r) * 1024 + t) * 512 + hcol, word);
    } else {
      out[((size_t)(brow + r) * 1024 + t) * 512 + hcol] = hn;
    }
    if (t == 1023) {
      hfinL[(size_t)(brow + r) * 512 + hcol] = hn;
      cfinL[(size_t)(brow + r) * 512 + hcol] = c;
    }
    // ---- prefetch next input + next h (issue only; completed next iter) ----
    if (t < 1023) {
      int tn = t + 1;
      if (layer == 0) {
        const short8* xsp = (const short8*)(xbf + ((size_t)(brow + mm) * 1024 + tn) * 512) + kq * 4;
        xv0 = xsp[0]; xv1 = xsp[1]; xv2 = xsp[2]; xv3 = xsp[3];
      } else {
        yp_cur = y0u + ((size_t)(brow + mm) * 1024 + tn) * 512 + kq * 32;
        issue8_sc1(yp_cur, yr0, yr1, yr2, yr3, yr4, yr5, yr6, yr7);
      }
      hp_cur = hbL + (size_t)(tn & 1) * 32768 + (size_t)(brow + mm) * 512 + kq * 32;
      issue8_sc1(hp_cur, hr0, hr1, hr2, hr3, hr4, hr5, hr6, hr7);
    }
  }
}

extern "C" void kernel_launch(void* const* d_in, const int* in_sizes, int n_in,
                              void* d_out, int out_size, void* d_ws, size_t ws_size,
                              hipStream_t stream) {
  const float* x   = (const float*)d_in[0];
  const float* Wx0 = (const float*)d_in[1];
  const float* Wh0 = (const float*)d_in[2];
  const float* b0  = (const float*)d_in[3];
  const float* Wx1 = (const float*)d_in[4];
  const float* Wh1 = (const float*)d_in[5];
  const float* b1  = (const float*)d_in[6];
  float* out = (float*)d_out;
  char* ws = (char*)d_ws;

  const size_t OFF_Y0   = 0;                       // 64*1024*512*4 = 134217728
  const size_t OFF_XBF  = 134217728;               // 64*1024*512*2 = 67108864
  const size_t OFF_WX0T = 201326592;               // 2MB each
  const size_t OFF_WH0T = 203423744;
  const size_t OFF_WX1T = 205520896;
  const size_t OFF_WH1T = 207618048;
  const size_t OFF_HB   = 209715200;               // 2*2*64*512*4 = 524288
  const size_t NEED     = OFF_HB + 524288;
  if (ws_size < NEED) return;

  unsigned int* y0u = (unsigned int*)(ws + OFF_Y0);
  u16* x_bf  = (u16*)(ws + OFF_XBF);
  u16* Wx0t  = (u16*)(ws + OFF_WX0T);
  u16* Wh0t  = (u16*)(ws + OFF_WH0T);
  u16* Wx1t  = (u16*)(ws + OFF_WX1T);
  u16* Wh1t  = (u16*)(ws + OFF_WH1T);
  unsigned int* hb  = (unsigned int*)(ws + OFF_HB);

  // clear tags (y0 + hb) every launch: stale tags from a previous replay
  // carry valid-looking values (re-poison safety)
  (void)hipMemsetAsync(ws + OFF_Y0, 0, 134217728, stream);
  (void)hipMemsetAsync(ws + OFF_HB, 0, 524288, stream);

  convert_f32_bf16<<<16384, 256, 0, stream>>>(x, x_bf, 4194304);
  transpose_to_bf16<<<dim3(8, 32), 256, 0, stream>>>(Wx0, Wx0t);
  transpose_to_bf16<<<dim3(8, 32), 256, 0, stream>>>(Wh0, Wh0t);
  transpose_to_bf16<<<dim3(8, 32), 256, 0, stream>>>(Wx1, Wx1t);
  transpose_to_bf16<<<dim3(8, 32), 256, 0, stream>>>(Wh1, Wh1t);

  float* hfin = out + 33554432;
  float* cfin = out + 33554432 + 65536;
  lstm_fused<<<256, 256, 0, stream>>>(x_bf, Wx0t, Wh0t, Wx1t, Wh1t, b0, b1,
                                      hb, y0u, out, hfin, cfin);
}